// Round 7
// baseline (507.368 us; speedup 1.0000x reference)
//
#include <hip/hip_runtime.h>
#include <hip/hip_bf16.h>

#define M_TOK 4096
#define K_DIM 4096
#define N_OUT 14336

typedef float f32x4 __attribute__((ext_vector_type(4)));
typedef short bf16x8 __attribute__((ext_vector_type(8)));
typedef unsigned short u16;
typedef unsigned int u32;
typedef u16 u16x8 __attribute__((ext_vector_type(8)));

__device__ __forceinline__ u16 f2bf_rne(float f) {
    u32 u = __builtin_bit_cast(u32, f);
    u += 0x7fffu + ((u >> 16) & 1u);
    return (u16)(u >> 16);
}

__device__ __forceinline__ void async16(const void* g, void* l) {
    __builtin_amdgcn_global_load_lds(
        (const __attribute__((address_space(1))) void*)g,
        (__attribute__((address_space(3))) void*)l, 16, 0, 0);
}

__device__ __forceinline__ void bar() {
    asm volatile("" ::: "memory");
    __builtin_amdgcn_s_barrier();
    asm volatile("" ::: "memory");
}

#define VMCNT(n) asm volatile("s_waitcnt vmcnt(" #n ")" ::: "memory")

// ---------------- merged conversion kernel (16 elems/thread) ----------------

__global__ __launch_bounds__(256) void cvt_all(const float* __restrict__ state,
                                               const float* __restrict__ w,
                                               const int* __restrict__ eid,
                                               u16* __restrict__ a16,
                                               u16* __restrict__ b16) {
    const size_t nA = (size_t)M_TOK * K_DIM;
    size_t base = ((size_t)blockIdx.x * 256 + threadIdx.x) * 16;
    const float* src;
    u16* dst;
    if (base < nA) {
        src = state + base;
        dst = a16 + base;
    } else {
        size_t j = base - nA;
        src = w + (size_t)(*eid) * ((size_t)N_OUT * K_DIM) + j;
        dst = b16 + j;
    }
    f32x4 v0 = *(const f32x4*)(src);
    f32x4 v1 = *(const f32x4*)(src + 4);
    f32x4 v2 = *(const f32x4*)(src + 8);
    f32x4 v3 = *(const f32x4*)(src + 12);
    u16x8 h0, h1;
    h0[0] = f2bf_rne(v0[0]); h0[1] = f2bf_rne(v0[1]);
    h0[2] = f2bf_rne(v0[2]); h0[3] = f2bf_rne(v0[3]);
    h0[4] = f2bf_rne(v1[0]); h0[5] = f2bf_rne(v1[1]);
    h0[6] = f2bf_rne(v1[2]); h0[7] = f2bf_rne(v1[3]);
    h1[0] = f2bf_rne(v2[0]); h1[1] = f2bf_rne(v2[1]);
    h1[2] = f2bf_rne(v2[2]); h1[3] = f2bf_rne(v2[3]);
    h1[4] = f2bf_rne(v3[0]); h1[5] = f2bf_rne(v3[1]);
    h1[6] = f2bf_rne(v3[2]); h1[7] = f2bf_rne(v3[3]);
    *(u16x8*)(dst) = h0;
    *(u16x8*)(dst + 8) = h1;
}

// ---------------- 256x256 8-phase bf16 GEMM body (proven round-2/4 schedule) --
// C[M,N] = A[M,K] * B[N,K]^T. BM=BN=256, BK=64, 8 waves (2Mx4N), 512 thr.
// LDS: [2][2][16384] u16, 128 KiB. XOR-swizzled 16B chunks: chunk (row, slot)
// holds logical col16 = slot ^ (row&7); global_load_lds dest is linear, the
// per-lane global SOURCE realizes the permutation.
// 16x16x32 MFMA, 16 per phase, 8 independent acc chains of depth 2 (do NOT
// swap to 32x32x16: round-5 showed chain-depth-4 stalls + bank conflicts).

template <int NKT>
__device__ __forceinline__ void gemm_body(const u16* __restrict__ A,
                                          const u16* __restrict__ B,
                                          float* __restrict__ out, int ldc,
                                          int orow, int ocol,
                                          int brow, int bcol, int k0t,
                                          u16* ldsb) {
    const int tid  = threadIdx.x;
    const int wid  = tid >> 6;
    const int lane = tid & 63;
    const int wr = wid >> 2;      // 0..1  (M)
    const int wc = wid & 3;       // 0..3  (N)

    const int rsel = lane >> 3;
    const int slot = lane & 7;
    const int scol = ((slot ^ rsel) << 3);
    u32 aoff[2][2], boff[2][2];
#pragma unroll
    for (int h = 0; h < 2; ++h)
#pragma unroll
        for (int c = 0; c < 2; ++c) {
            const int row = h * 128 + wid * 8 + c * 64 + rsel;
            aoff[h][c] = (u32)(brow + row) * K_DIM + scol + (u32)k0t * 64;
            boff[h][c] = (u32)(bcol + row) * K_DIM + scol + (u32)k0t * 64;
        }

    const int la = lane & 15, kb = lane >> 4, l7 = lane & 7;
    const int aB[2] = {(wr * 128 + la) * 64 + ((kb ^ l7) << 3),
                       (wr * 128 + la) * 64 + (((4 + kb) ^ l7) << 3)};
    const int bB[2] = {(wc * 64 + la) * 64 + ((kb ^ l7) << 3),
                       (wc * 64 + la) * 64 + (((4 + kb) ^ l7) << 3)};

    f32x4 acc[8][4] = {};
    bf16x8 aF0[4][2], aF1[4][2], bF[2][2];

#define STAGE_A(buf, h, kt) do { \
    async16(A + aoff[h][0] + (u32)(kt) * 64, ldsb + (buf) * 32768 + (h) * 8192 + wid * 512); \
    async16(A + aoff[h][1] + (u32)(kt) * 64, ldsb + (buf) * 32768 + (h) * 8192 + wid * 512 + 4096); \
} while (0)
#define STAGE_B(buf, h, kt) do { \
    async16(B + boff[h][0] + (u32)(kt) * 64, ldsb + (buf) * 32768 + 16384 + (h) * 8192 + wid * 512); \
    async16(B + boff[h][1] + (u32)(kt) * 64, ldsb + (buf) * 32768 + 16384 + (h) * 8192 + wid * 512 + 4096); \
} while (0)

#define LD_A0(buf) do { \
    _Pragma("unroll") for (int m = 0; m < 4; ++m) \
    _Pragma("unroll") for (int ks = 0; ks < 2; ++ks) \
        aF0[m][ks] = *(const bf16x8*)&ldsb[(buf) * 32768 + aB[ks] + m * 1024]; \
} while (0)
#define LD_A1(buf) do { \
    _Pragma("unroll") for (int m = 0; m < 4; ++m) \
    _Pragma("unroll") for (int ks = 0; ks < 2; ++ks) \
        aF1[m][ks] = *(const bf16x8*)&ldsb[(buf) * 32768 + aB[ks] + (m + 4) * 1024]; \
} while (0)
#define LD_B01(buf) do { \
    _Pragma("unroll") for (int n = 0; n < 2; ++n) \
    _Pragma("unroll") for (int ks = 0; ks < 2; ++ks) \
        bF[n][ks] = *(const bf16x8*)&ldsb[(buf) * 32768 + 16384 + bB[ks] + n * 1024]; \
} while (0)
#define LD_B23(buf) do { \
    _Pragma("unroll") for (int n = 0; n < 2; ++n) \
    _Pragma("unroll") for (int ks = 0; ks < 2; ++ks) \
        bF[n][ks] = *(const bf16x8*)&ldsb[(buf) * 32768 + 16384 + bB[ks] + (n + 2) * 1024]; \
} while (0)

#define MMQ(AA, QM, QN) do { \
    __builtin_amdgcn_s_setprio(1); \
    _Pragma("unroll") for (int m = 0; m < 4; ++m) \
    _Pragma("unroll") for (int n = 0; n < 2; ++n) \
    _Pragma("unroll") for (int ks = 0; ks < 2; ++ks) \
        acc[(QM) * 4 + m][(QN) * 2 + n] = __builtin_amdgcn_mfma_f32_16x16x32_bf16( \
            AA[m][ks], bF[n][ks], acc[(QM) * 4 + m][(QN) * 2 + n], 0, 0, 0); \
    __builtin_amdgcn_s_setprio(0); \
} while (0)

    STAGE_A(0, 0, 0); STAGE_A(0, 1, 0); STAGE_B(0, 0, 0); STAGE_B(0, 1, 0);
    STAGE_A(1, 0, 1);
    STAGE_A(1, 1, 1); STAGE_B(1, 0, 1);
    VMCNT(6);
    __builtin_amdgcn_s_barrier();
    asm volatile("" ::: "memory");

#pragma unroll 1
    for (int it = 0; it < NKT / 2; ++it) {
        const int t1 = 2 * it + 1;
        const int t2 = (2 * it + 2) & (NKT - 1);
        const int t3 = (2 * it + 3) & (NKT - 1);
        // P1
        LD_A0(0); LD_B01(0);
        STAGE_B(1, 1, t1);
        bar(); MMQ(aF0, 0, 0); bar();
        // P2
        LD_A1(0);
        bar(); MMQ(aF1, 1, 0); bar();
        // P3
        LD_B23(0);
        STAGE_A(0, 0, t2);
        bar(); MMQ(aF0, 0, 1); bar();
        // P4
        STAGE_A(0, 1, t2); STAGE_B(0, 0, t2);
        bar(); MMQ(aF1, 1, 1);
        VMCNT(6); bar();
        // P5
        LD_A0(1); LD_B01(1);
        STAGE_B(0, 1, t2);
        bar(); MMQ(aF0, 0, 0); bar();
        // P6
        LD_A1(1);
        bar(); MMQ(aF1, 1, 0); bar();
        // P7
        LD_B23(1);
        STAGE_A(1, 0, t3);
        bar(); MMQ(aF0, 0, 1); bar();
        // P8
        STAGE_A(1, 1, t3); STAGE_B(1, 0, t3);
        bar(); MMQ(aF1, 1, 1);
        VMCNT(6); bar();
    }

    asm volatile("" ::: "memory");
#pragma unroll
    for (int mi = 0; mi < 8; ++mi)
#pragma unroll
        for (int n = 0; n < 4; ++n) {
            float* cp = out + (size_t)(orow + wr * 128 + mi * 16 + kb * 4) * (size_t)ldc
                            + (ocol + wc * 64 + n * 16 + la);
#pragma unroll
            for (int j = 0; j < 4; ++j)
                cp[(size_t)j * ldc] = acc[mi][n][j];
        }

#undef STAGE_A
#undef STAGE_B
#undef LD_A0
#undef LD_A1
#undef LD_B01
#undef LD_B23
#undef MMQ
}

// Main: rectangle by[0,16) x bx[0,48) = 768 tiles. Locality map assuming
// dispatch round-robin (XCD ~ bid&7): XCD x owns bx in [6x, 6x+6); each
// 256-block round walks a 16(by) x 2(bx) strip -> 2 B-panels (4MB) L2-hot
// reused 16x, A streams. Bijective.
__global__ __launch_bounds__(512, 2) void gemm256_main(const u16* __restrict__ A,
                                                       const u16* __restrict__ B,
                                                       float* __restrict__ C) {
    __shared__ __align__(16) u16 lds[2][2][16384];
    const int bid = blockIdx.x;
    const int x = bid & 7;          // XCD
    const int i = bid >> 3;         // 0..95 within region
    const int s = i >> 5;           // strip (round) 0..2
    const int j = i & 31;
    const int by = j >> 1;
    const int bx = 6 * x + 2 * s + (j & 1);
    gemm_body<64>(A, B, C, N_OUT, by * 256, bx * 256, by * 256, bx * 256, 0,
                  &lds[0][0][0]);
}

// Split-K remainder: columns bx in [48,56) x by[0,16), 2 K-halves = 256 blocks.
// XCD x owns column 48+x: its B-panel stays L2-hot; both K-halves of a tile
// read the same bytes on the same XCD.
__global__ __launch_bounds__(512, 2) void gemm256_tailk(const u16* __restrict__ A,
                                                        const u16* __restrict__ B,
                                                        float* __restrict__ C,
                                                        float* __restrict__ ws) {
    __shared__ __align__(16) u16 lds[2][2][16384];
    const int bid = blockIdx.x;
    const int x = bid & 7;
    const int i = bid >> 3;         // 0..31
    const int by = i & 15;
    const int kh = i >> 4;
    const int bx = 48 + x;
    const int tb = x * 16 + by;     // ws slot, 0..127
    if (kh == 0) {
        gemm_body<32>(A, B, C, N_OUT, by * 256, bx * 256, by * 256, bx * 256, 0,
                      &lds[0][0][0]);
    } else {
        gemm_body<32>(A, B, ws + (size_t)tb * 65536, 256, 0, 0,
                      by * 256, bx * 256, 32, &lds[0][0][0]);
    }
}

// Full-K tail for the no-split-K fallback path: 128 blocks, one per tile.
__global__ __launch_bounds__(512, 2) void gemm256_tailfull(const u16* __restrict__ A,
                                                           const u16* __restrict__ B,
                                                           float* __restrict__ C) {
    __shared__ __align__(16) u16 lds[2][2][16384];
    const int bid = blockIdx.x;
    const int x = bid & 7;
    const int i = bid >> 3;         // 0..15
    const int by = i;
    const int bx = 48 + x;
    gemm_body<64>(A, B, C, N_OUT, by * 256, bx * 256, by * 256, bx * 256, 0,
                  &lds[0][0][0]);
}

// C[tail region] += ws partials. tb -> (by = tb&15, bx = 48 + tb/16).
__global__ __launch_bounds__(256) void reduce_tail(const float* __restrict__ ws,
                                                   float* __restrict__ C) {
    const int bid = blockIdx.x;
    const int tb = bid >> 4;
    const int rg = bid & 15;
    const int by = tb & 15;
    const int bx = 48 + (tb >> 4);
    const float* src = ws + (size_t)tb * 65536 + rg * 4096;
    float* dst = C + (size_t)(by * 256 + rg * 16) * N_OUT + bx * 256;
    const int tidx = threadIdx.x;
#pragma unroll
    for (int p = 0; p < 4; ++p) {
        const int e = p * 1024 + tidx * 4;
        const int r = e >> 8, c = e & 255;
        f32x4 v = *(const f32x4*)(src + e);
        float* d = dst + (size_t)r * N_OUT + c;
        f32x4 o = *(const f32x4*)d;
        o[0] += v[0]; o[1] += v[1]; o[2] += v[2]; o[3] += v[3];
        *(f32x4*)d = o;
    }
}

// ---------------- fused-conversion fallback (no workspace) ----------------

__global__ __launch_bounds__(256) void gemm_fused(const float* __restrict__ Af,
                                                  const float* __restrict__ Wf,
                                                  const int* __restrict__ eid,
                                                  float* __restrict__ C) {
    const float* Bf = Wf + (size_t)(*eid) * ((size_t)N_OUT * K_DIM);

    __shared__ __align__(16) u16 As[2][4096];
    __shared__ __align__(16) u16 Bs[2][4096];

    const int tid  = threadIdx.x;
    const int wid  = tid >> 6;
    const int lane = tid & 63;
    const int brow = blockIdx.y * 128;
    const int bcol = blockIdx.x * 128;
    const int wr = wid >> 1, wc = wid & 1;

    f32x4 acc[4][4] = {};

    auto stage = [&](int buf, int kt) {
#pragma unroll
        for (int i = 0; i < 2; ++i) {
            const int l = tid + i * 256;
            const int g = l >> 6, c4 = (l >> 4) & 3, r = l & 15;
            {
                const size_t base = (size_t)(brow + g * 16 + r) * K_DIM + c4 * 8 + kt * 32;
                f32x4 v0 = *(const f32x4*)(Af + base);
                f32x4 v1 = *(const f32x4*)(Af + base + 4);
                u16x8 h;
                h[0] = f2bf_rne(v0[0]); h[1] = f2bf_rne(v0[1]);
                h[2] = f2bf_rne(v0[2]); h[3] = f2bf_rne(v0[3]);
                h[4] = f2bf_rne(v1[0]); h[5] = f2bf_rne(v1[1]);
                h[6] = f2bf_rne(v1[2]); h[7] = f2bf_rne(v1[3]);
                *(u16x8*)&As[buf][l * 8] = h;
            }
            {
                const size_t base = (size_t)(bcol + g * 16 + r) * K_DIM + c4 * 8 + kt * 32;
                f32x4 v0 = *(const f32x4*)(Bf + base);
                f32x4 v1 = *(const f32x4*)(Bf + base + 4);
                u16x8 h;
                h[0] = f2bf_rne(v0[0]); h[1] = f2bf_rne(v0[1]);
                h[2] = f2bf_rne(v0[2]); h[3] = f2bf_rne(v0[3]);
                h[4] = f2bf_rne(v1[0]); h[5] = f2bf_rne(v1[1]);
                h[6] = f2bf_rne(v1[2]); h[7] = f2bf_rne(v1[3]);
                *(u16x8*)&Bs[buf][l * 8] = h;
            }
        }
    };

    auto compute = [&](int buf) {
        bf16x8 a[4], b[4];
#pragma unroll
        for (int m = 0; m < 4; ++m)
            a[m] = *(const bf16x8*)&As[buf][(wr * 4 + m) * 512 + lane * 8];
#pragma unroll
        for (int n = 0; n < 4; ++n)
            b[n] = *(const bf16x8*)&Bs[buf][(wc * 4 + n) * 512 + lane * 8];
#pragma unroll
        for (int m = 0; m < 4; ++m)
#pragma unroll
            for (int n = 0; n < 4; ++n)
                acc[m][n] = __builtin_amdgcn_mfma_f32_16x16x32_bf16(a[m], b[n], acc[m][n], 0, 0, 0);
    };

    stage(0, 0);
    __syncthreads();
    int cur = 0;
#pragma unroll 1
    for (int kt = 0; kt < (K_DIM / 32) - 1; ++kt) {
        stage(cur ^ 1, kt + 1);
        compute(cur);
        __syncthreads();
        cur ^= 1;
    }
    compute(cur);

    const int r0 = (lane >> 4) * 4;
    const int cn = lane & 15;
#pragma unroll
    for (int m = 0; m < 4; ++m)
#pragma unroll
        for (int n = 0; n < 4; ++n) {
            float* cp = C + (size_t)(brow + wr * 64 + m * 16 + r0) * N_OUT
                          + (bcol + wc * 64 + n * 16 + cn);
#pragma unroll
            for (int j = 0; j < 4; ++j)
                cp[(size_t)j * N_OUT] = acc[m][n][j];
        }
}

// ---------------- launch ----------------

extern "C" void kernel_launch(void* const* d_in, const int* in_sizes, int n_in,
                              void* d_out, int out_size, void* d_ws, size_t ws_size,
                              hipStream_t stream) {
    const float* state = (const float*)d_in[0];
    const float* w     = (const float*)d_in[1];
    const int*   eid   = (const int*)d_in[2];
    float*       out   = (float*)d_out;

    const size_t nA = (size_t)M_TOK * K_DIM;   // 16,777,216
    const size_t nB = (size_t)N_OUT * K_DIM;   // 58,720,256
    const size_t needA = (nA + nB) * sizeof(u16);              // 150,994,944
    const size_t needB = needA + (size_t)128 * 65536 * 4;      // +32 MiB partials

    if (d_ws != nullptr && ws_size >= needB) {
        u16* a16 = (u16*)d_ws;
        u16* b16 = a16 + nA;
        float* wsC = (float*)((char*)d_ws + needA);
        cvt_all<<<(unsigned)((nA + nB) / 4096), 256, 0, stream>>>(state, w, eid, a16, b16);
        gemm256_main<<<768, 512, 0, stream>>>(a16, b16, out);
        gemm256_tailk<<<256, 512, 0, stream>>>(a16, b16, out, wsC);
        reduce_tail<<<2048, 256, 0, stream>>>(wsC, out);
    } else if (d_ws != nullptr && ws_size >= needA) {
        u16* a16 = (u16*)d_ws;
        u16* b16 = a16 + nA;
        cvt_all<<<(unsigned)((nA + nB) / 4096), 256, 0, stream>>>(state, w, eid, a16, b16);
        gemm256_main<<<768, 512, 0, stream>>>(a16, b16, out);
        gemm256_tailfull<<<128, 512, 0, stream>>>(a16, b16, out);
    } else {
        dim3 grid(N_OUT / 128, M_TOK / 128);
        gemm_fused<<<grid, 256, 0, stream>>>(state, w, eid, out);
    }
}

// Round 8
// 487.979 us; speedup vs baseline: 1.0397x; 1.0397x over previous
//
#include <hip/hip_runtime.h>
#include <hip/hip_bf16.h>

#define M_TOK 4096
#define K_DIM 4096
#define N_OUT 14336

typedef float f32x4 __attribute__((ext_vector_type(4)));
typedef short bf16x8 __attribute__((ext_vector_type(8)));
typedef unsigned short u16;
typedef unsigned int u32;
typedef u16 u16x8 __attribute__((ext_vector_type(8)));

__device__ __forceinline__ u16 f2bf_rne(float f) {
    u32 u = __builtin_bit_cast(u32, f);
    u += 0x7fffu + ((u >> 16) & 1u);
    return (u16)(u >> 16);
}

__device__ __forceinline__ void async16(const void* g, void* l) {
    __builtin_amdgcn_global_load_lds(
        (const __attribute__((address_space(1))) void*)g,
        (__attribute__((address_space(3))) void*)l, 16, 0, 0);
}

__device__ __forceinline__ void bar() {
    asm volatile("" ::: "memory");
    __builtin_amdgcn_s_barrier();
    asm volatile("" ::: "memory");
}

#define VMCNT(n) asm volatile("s_waitcnt vmcnt(" #n ")" ::: "memory")

// ---------------- merged conversion kernel (16 elems/thread) ----------------

__global__ __launch_bounds__(256) void cvt_all(const float* __restrict__ state,
                                               const float* __restrict__ w,
                                               const int* __restrict__ eid,
                                               u16* __restrict__ a16,
                                               u16* __restrict__ b16) {
    const size_t nA = (size_t)M_TOK * K_DIM;
    size_t base = ((size_t)blockIdx.x * 256 + threadIdx.x) * 16;
    const float* src;
    u16* dst;
    if (base < nA) {
        src = state + base;
        dst = a16 + base;
    } else {
        size_t j = base - nA;
        src = w + (size_t)(*eid) * ((size_t)N_OUT * K_DIM) + j;
        dst = b16 + j;
    }
    f32x4 v0 = *(const f32x4*)(src);
    f32x4 v1 = *(const f32x4*)(src + 4);
    f32x4 v2 = *(const f32x4*)(src + 8);
    f32x4 v3 = *(const f32x4*)(src + 12);
    u16x8 h0, h1;
    h0[0] = f2bf_rne(v0[0]); h0[1] = f2bf_rne(v0[1]);
    h0[2] = f2bf_rne(v0[2]); h0[3] = f2bf_rne(v0[3]);
    h0[4] = f2bf_rne(v1[0]); h0[5] = f2bf_rne(v1[1]);
    h0[6] = f2bf_rne(v1[2]); h0[7] = f2bf_rne(v1[3]);
    h1[0] = f2bf_rne(v2[0]); h1[1] = f2bf_rne(v2[1]);
    h1[2] = f2bf_rne(v2[2]); h1[3] = f2bf_rne(v2[3]);
    h1[4] = f2bf_rne(v3[0]); h1[5] = f2bf_rne(v3[1]);
    h1[6] = f2bf_rne(v3[2]); h1[7] = f2bf_rne(v3[3]);
    *(u16x8*)(dst) = h0;
    *(u16x8*)(dst + 8) = h1;
}

// ---------------- 256x256 8-phase bf16 GEMM body ----------------
// C[M,N] = A[M,K] * B[N,K]^T. BM=BN=256, BK=64, 8 waves (2Mx4N), 512 thr.
// LDS: [2][2][16384] u16, 128 KiB. XOR-swizzled 16B chunks: chunk (row, slot)
// holds logical col16 = slot ^ (row&7); global_load_lds dest is linear, the
// per-lane global SOURCE realizes the permutation.
// 16x16x32 MFMA, 16 per phase (8 indep acc chains of depth 2; round-5: do NOT
// use 32x32x16 -- chain-depth-4 stalls + bank conflicts, 489->541).
// ds_reads balanced 8/8/4/4 per half-iter (round-7): LD_B01 for phase P(4k+1)
// is issued at the end of the previous vmcnt-phase, after its vmcnt(6) proved
// the staged B-half complete (ledger: P4's vmcnt(6) completes everything
// issued <= P1; buf1-B-half0 was staged at prev-P8 < P1. P8's vmcnt(6)
// completes <= P5; buf0-B-half0 staged at P4 < P5).

template <int NKT>
__device__ __forceinline__ void gemm_body(const u16* __restrict__ A,
                                          const u16* __restrict__ B,
                                          float* __restrict__ out, int ldc,
                                          int orow, int ocol,
                                          int brow, int bcol, int k0t,
                                          u16* ldsb) {
    const int tid  = threadIdx.x;
    const int wid  = tid >> 6;
    const int lane = tid & 63;
    const int wr = wid >> 2;      // 0..1  (M)
    const int wc = wid & 3;       // 0..3  (N)

    const int rsel = lane >> 3;
    const int slot = lane & 7;
    const int scol = ((slot ^ rsel) << 3);
    u32 aoff[2][2], boff[2][2];
#pragma unroll
    for (int h = 0; h < 2; ++h)
#pragma unroll
        for (int c = 0; c < 2; ++c) {
            const int row = h * 128 + wid * 8 + c * 64 + rsel;
            aoff[h][c] = (u32)(brow + row) * K_DIM + scol + (u32)k0t * 64;
            boff[h][c] = (u32)(bcol + row) * K_DIM + scol + (u32)k0t * 64;
        }

    const int la = lane & 15, kb = lane >> 4, l7 = lane & 7;
    const int aB[2] = {(wr * 128 + la) * 64 + ((kb ^ l7) << 3),
                       (wr * 128 + la) * 64 + (((4 + kb) ^ l7) << 3)};
    const int bB[2] = {(wc * 64 + la) * 64 + ((kb ^ l7) << 3),
                       (wc * 64 + la) * 64 + (((4 + kb) ^ l7) << 3)};

    f32x4 acc[8][4] = {};
    bf16x8 aF0[4][2], aF1[4][2], bF[2][2];

#define STAGE_A(buf, h, kt) do { \
    async16(A + aoff[h][0] + (u32)(kt) * 64, ldsb + (buf) * 32768 + (h) * 8192 + wid * 512); \
    async16(A + aoff[h][1] + (u32)(kt) * 64, ldsb + (buf) * 32768 + (h) * 8192 + wid * 512 + 4096); \
} while (0)
#define STAGE_B(buf, h, kt) do { \
    async16(B + boff[h][0] + (u32)(kt) * 64, ldsb + (buf) * 32768 + 16384 + (h) * 8192 + wid * 512); \
    async16(B + boff[h][1] + (u32)(kt) * 64, ldsb + (buf) * 32768 + 16384 + (h) * 8192 + wid * 512 + 4096); \
} while (0)

#define LD_A0(buf) do { \
    _Pragma("unroll") for (int m = 0; m < 4; ++m) \
    _Pragma("unroll") for (int ks = 0; ks < 2; ++ks) \
        aF0[m][ks] = *(const bf16x8*)&ldsb[(buf) * 32768 + aB[ks] + m * 1024]; \
} while (0)
#define LD_A1(buf) do { \
    _Pragma("unroll") for (int m = 0; m < 4; ++m) \
    _Pragma("unroll") for (int ks = 0; ks < 2; ++ks) \
        aF1[m][ks] = *(const bf16x8*)&ldsb[(buf) * 32768 + aB[ks] + (m + 4) * 1024]; \
} while (0)
#define LD_B01(buf) do { \
    _Pragma("unroll") for (int n = 0; n < 2; ++n) \
    _Pragma("unroll") for (int ks = 0; ks < 2; ++ks) \
        bF[n][ks] = *(const bf16x8*)&ldsb[(buf) * 32768 + 16384 + bB[ks] + n * 1024]; \
} while (0)
#define LD_B23(buf) do { \
    _Pragma("unroll") for (int n = 0; n < 2; ++n) \
    _Pragma("unroll") for (int ks = 0; ks < 2; ++ks) \
        bF[n][ks] = *(const bf16x8*)&ldsb[(buf) * 32768 + 16384 + bB[ks] + (n + 2) * 1024]; \
} while (0)

#define MMQ(AA, QM, QN) do { \
    __builtin_amdgcn_s_setprio(1); \
    _Pragma("unroll") for (int m = 0; m < 4; ++m) \
    _Pragma("unroll") for (int n = 0; n < 2; ++n) \
    _Pragma("unroll") for (int ks = 0; ks < 2; ++ks) \
        acc[(QM) * 4 + m][(QN) * 2 + n] = __builtin_amdgcn_mfma_f32_16x16x32_bf16( \
            AA[m][ks], bF[n][ks], acc[(QM) * 4 + m][(QN) * 2 + n], 0, 0, 0); \
    __builtin_amdgcn_s_setprio(0); \
} while (0)

    STAGE_A(0, 0, 0); STAGE_A(0, 1, 0); STAGE_B(0, 0, 0); STAGE_B(0, 1, 0);
    STAGE_A(1, 0, 1);
    STAGE_A(1, 1, 1); STAGE_B(1, 0, 1);
    VMCNT(6);
    __builtin_amdgcn_s_barrier();
    asm volatile("" ::: "memory");
    LD_B01(0);   // buf0 fully staged; pre-load B cols 0-1 for P1/P2

#pragma unroll 1
    for (int it = 0; it < NKT / 2; ++it) {
        const int t1 = 2 * it + 1;
        const int t2 = (2 * it + 2) & (NKT - 1);
        const int t3 = (2 * it + 3) & (NKT - 1);
        // P1  (8 ds_reads; bF holds B01(buf0) from prev P8 / pre-loop)
        LD_A0(0);
        STAGE_B(1, 1, t1);
        bar(); MMQ(aF0, 0, 0); bar();
        // P2  (8 reads)
        LD_A1(0);
        bar(); MMQ(aF1, 1, 0); bar();
        // P3  (4 reads)
        LD_B23(0);
        STAGE_A(0, 0, t2);
        bar(); MMQ(aF0, 0, 1); bar();
        // P4  (4 reads, post-vmcnt: buf1 B01 proven complete)
        STAGE_A(0, 1, t2); STAGE_B(0, 0, t2);
        bar(); MMQ(aF1, 1, 1);
        VMCNT(6);
        LD_B01(1);
        bar();
        // P5  (8 reads)
        LD_A0(1);
        STAGE_B(0, 1, t2);
        bar(); MMQ(aF0, 0, 0); bar();
        // P6  (8 reads)
        LD_A1(1);
        bar(); MMQ(aF1, 1, 0); bar();
        // P7  (4 reads)
        LD_B23(1);
        STAGE_A(1, 0, t3);
        bar(); MMQ(aF0, 0, 1); bar();
        // P8  (4 reads, post-vmcnt: buf0 B01(t2) proven complete)
        STAGE_A(1, 1, t3); STAGE_B(1, 0, t3);
        bar(); MMQ(aF1, 1, 1);
        VMCNT(6);
        LD_B01(0);
        bar();
    }

    asm volatile("" ::: "memory");
#pragma unroll
    for (int mi = 0; mi < 8; ++mi)
#pragma unroll
        for (int n = 0; n < 4; ++n) {
            float* cp = out + (size_t)(orow + wr * 128 + mi * 16 + kb * 4) * (size_t)ldc
                            + (ocol + wc * 64 + n * 16 + la);
#pragma unroll
            for (int j = 0; j < 4; ++j)
                cp[(size_t)j * ldc] = acc[mi][n][j];
        }

#undef STAGE_A
#undef STAGE_B
#undef LD_A0
#undef LD_A1
#undef LD_B01
#undef LD_B23
#undef MMQ
}

// Main: tiles 0..767, plain x-major raster (round-4 proven best; round-7's
// XCD strip remap regressed -18us: concurrent blocks on an XCD already share
// the A-panel under this raster).
__global__ __launch_bounds__(512, 2) void gemm256_main(const u16* __restrict__ A,
                                                       const u16* __restrict__ B,
                                                       float* __restrict__ C) {
    __shared__ __align__(16) u16 lds[2][2][16384];
    const int tile = blockIdx.x;
    const int by = tile / 56, bx = tile % 56;
    gemm_body<64>(A, B, C, N_OUT, by * 256, bx * 256, by * 256, bx * 256, 0,
                  &lds[0][0][0]);
}

// Split-K remainder: 256 blocks cover tiles 768..895, two K-halves each.
__global__ __launch_bounds__(512, 2) void gemm256_tailk(const u16* __restrict__ A,
                                                        const u16* __restrict__ B,
                                                        float* __restrict__ C,
                                                        float* __restrict__ ws) {
    __shared__ __align__(16) u16 lds[2][2][16384];
    const int bid = blockIdx.x;
    const int tb = bid & 127;
    const int kh = bid >> 7;
    const int tile = 768 + tb;
    const int by = tile / 56, bx = tile % 56;
    if (kh == 0) {
        gemm_body<32>(A, B, C, N_OUT, by * 256, bx * 256, by * 256, bx * 256, 0,
                      &lds[0][0][0]);
    } else {
        gemm_body<32>(A, B, ws + (size_t)tb * 65536, 256, 0, 0,
                      by * 256, bx * 256, 32, &lds[0][0][0]);
    }
}

// Full-K tail for the no-split-K fallback path: 128 blocks, one per tile.
__global__ __launch_bounds__(512, 2) void gemm256_tailfull(const u16* __restrict__ A,
                                                           const u16* __restrict__ B,
                                                           float* __restrict__ C) {
    __shared__ __align__(16) u16 lds[2][2][16384];
    const int tile = 768 + blockIdx.x;
    const int by = tile / 56, bx = tile % 56;
    gemm_body<64>(A, B, C, N_OUT, by * 256, bx * 256, by * 256, bx * 256, 0,
                  &lds[0][0][0]);
}

// C[tail region] += ws partials. tb -> tile 768+tb (raster).
__global__ __launch_bounds__(256) void reduce_tail(const float* __restrict__ ws,
                                                   float* __restrict__ C) {
    const int bid = blockIdx.x;
    const int tb = bid >> 4;
    const int rg = bid & 15;
    const int tile = 768 + tb;
    const int by = tile / 56, bx = tile % 56;
    const float* src = ws + (size_t)tb * 65536 + rg * 4096;
    float* dst = C + (size_t)(by * 256 + rg * 16) * N_OUT + bx * 256;
    const int tidx = threadIdx.x;
#pragma unroll
    for (int p = 0; p < 4; ++p) {
        const int e = p * 1024 + tidx * 4;
        const int r = e >> 8, c = e & 255;
        f32x4 v = *(const f32x4*)(src + e);
        float* d = dst + (size_t)r * N_OUT + c;
        f32x4 o = *(const f32x4*)d;
        o[0] += v[0]; o[1] += v[1]; o[2] += v[2]; o[3] += v[3];
        *(f32x4*)d = o;
    }
}

// ---------------- fused-conversion fallback (no workspace) ----------------

__global__ __launch_bounds__(256) void gemm_fused(const float* __restrict__ Af,
                                                  const float* __restrict__ Wf,
                                                  const int* __restrict__ eid,
                                                  float* __restrict__ C) {
    const float* Bf = Wf + (size_t)(*eid) * ((size_t)N_OUT * K_DIM);

    __shared__ __align__(16) u16 As[2][4096];
    __shared__ __align__(16) u16 Bs[2][4096];

    const int tid  = threadIdx.x;
    const int wid  = tid >> 6;
    const int lane = tid & 63;
    const int brow = blockIdx.y * 128;
    const int bcol = blockIdx.x * 128;
    const int wr = wid >> 1, wc = wid & 1;

    f32x4 acc[4][4] = {};

    auto stage = [&](int buf, int kt) {
#pragma unroll
        for (int i = 0; i < 2; ++i) {
            const int l = tid + i * 256;
            const int g = l >> 6, c4 = (l >> 4) & 3, r = l & 15;
            {
                const size_t base = (size_t)(brow + g * 16 + r) * K_DIM + c4 * 8 + kt * 32;
                f32x4 v0 = *(const f32x4*)(Af + base);
                f32x4 v1 = *(const f32x4*)(Af + base + 4);
                u16x8 h;
                h[0] = f2bf_rne(v0[0]); h[1] = f2bf_rne(v0[1]);
                h[2] = f2bf_rne(v0[2]); h[3] = f2bf_rne(v0[3]);
                h[4] = f2bf_rne(v1[0]); h[5] = f2bf_rne(v1[1]);
                h[6] = f2bf_rne(v1[2]); h[7] = f2bf_rne(v1[3]);
                *(u16x8*)&As[buf][l * 8] = h;
            }
            {
                const size_t base = (size_t)(bcol + g * 16 + r) * K_DIM + c4 * 8 + kt * 32;
                f32x4 v0 = *(const f32x4*)(Bf + base);
                f32x4 v1 = *(const f32x4*)(Bf + base + 4);
                u16x8 h;
                h[0] = f2bf_rne(v0[0]); h[1] = f2bf_rne(v0[1]);
                h[2] = f2bf_rne(v0[2]); h[3] = f2bf_rne(v0[3]);
                h[4] = f2bf_rne(v1[0]); h[5] = f2bf_rne(v1[1]);
                h[6] = f2bf_rne(v1[2]); h[7] = f2bf_rne(v1[3]);
                *(u16x8*)&Bs[buf][l * 8] = h;
            }
        }
    };

    auto compute = [&](int buf) {
        bf16x8 a[4], b[4];
#pragma unroll
        for (int m = 0; m < 4; ++m)
            a[m] = *(const bf16x8*)&As[buf][(wr * 4 + m) * 512 + lane * 8];
#pragma unroll
        for (int n = 0; n < 4; ++n)
            b[n] = *(const bf16x8*)&Bs[buf][(wc * 4 + n) * 512 + lane * 8];
#pragma unroll
        for (int m = 0; m < 4; ++m)
#pragma unroll
            for (int n = 0; n < 4; ++n)
                acc[m][n] = __builtin_amdgcn_mfma_f32_16x16x32_bf16(a[m], b[n], acc[m][n], 0, 0, 0);
    };

    stage(0, 0);
    __syncthreads();
    int cur = 0;
#pragma unroll 1
    for (int kt = 0; kt < (K_DIM / 32) - 1; ++kt) {
        stage(cur ^ 1, kt + 1);
        compute(cur);
        __syncthreads();
        cur ^= 1;
    }
    compute(cur);

    const int r0 = (lane >> 4) * 4;
    const int cn = lane & 15;
#pragma unroll
    for (int m = 0; m < 4; ++m)
#pragma unroll
        for (int n = 0; n < 4; ++n) {
            float* cp = C + (size_t)(brow + wr * 64 + m * 16 + r0) * N_OUT
                          + (bcol + wc * 64 + n * 16 + cn);
#pragma unroll
            for (int j = 0; j < 4; ++j)
                cp[(size_t)j * N_OUT] = acc[m][n][j];
        }
}

// ---------------- launch ----------------

extern "C" void kernel_launch(void* const* d_in, const int* in_sizes, int n_in,
                              void* d_out, int out_size, void* d_ws, size_t ws_size,
                              hipStream_t stream) {
    const float* state = (const float*)d_in[0];
    const float* w     = (const float*)d_in[1];
    const int*   eid   = (const int*)d_in[2];
    float*       out   = (float*)d_out;

    const size_t nA = (size_t)M_TOK * K_DIM;   // 16,777,216
    const size_t nB = (size_t)N_OUT * K_DIM;   // 58,720,256
    const size_t needA = (nA + nB) * sizeof(u16);              // 150,994,944
    const size_t needB = needA + (size_t)128 * 65536 * 4;      // +32 MiB partials

    if (d_ws != nullptr && ws_size >= needB) {
        u16* a16 = (u16*)d_ws;
        u16* b16 = a16 + nA;
        float* wsC = (float*)((char*)d_ws + needA);
        cvt_all<<<(unsigned)((nA + nB) / 4096), 256, 0, stream>>>(state, w, eid, a16, b16);
        gemm256_main<<<768, 512, 0, stream>>>(a16, b16, out);
        gemm256_tailk<<<256, 512, 0, stream>>>(a16, b16, out, wsC);
        reduce_tail<<<2048, 256, 0, stream>>>(wsC, out);
    } else if (d_ws != nullptr && ws_size >= needA) {
        u16* a16 = (u16*)d_ws;
        u16* b16 = a16 + nA;
        cvt_all<<<(unsigned)((nA + nB) / 4096), 256, 0, stream>>>(state, w, eid, a16, b16);
        gemm256_main<<<768, 512, 0, stream>>>(a16, b16, out);
        gemm256_tailfull<<<128, 512, 0, stream>>>(a16, b16, out);
    } else {
        dim3 grid(N_OUT / 128, M_TOK / 128);
        gemm_fused<<<grid, 256, 0, stream>>>(state, w, eid, out);
    }
}